// Round 8
// baseline (475.569 us; speedup 1.0000x reference)
//
#include <hip/hip_runtime.h>
#include <math.h>

// CapsuleLayer routing on MI355X (gfx950). fp32 in/out.
// B=64, n=2048, k=32, in_C=16, out_C=32, 3 routing iterations.
//
// Fast path: materialize priors bf16 once via MFMA (k1) into [n][b][k][o];
// iterations 1/2 (k23) are wave-autonomous streaming passes (shfl softmax,
// no LDS/barriers).
// Round-8 change: k23 processes 4 nodes INTERLEAVED (4 independent
// dot->exp->5-hop-butterfly->div chains pipeline each other) with 4-node
// group prefetch. Round-7's 2-pair interleave left k23 at ~140us / 2 TB/s
// (latency-bound); k1's scalar-sweep stores (coalesced) stay as-is.

#define BATCH 64
#define NN    2048
#define NK    32
#define NI    16
#define NO    32

#define K1_CHUNK 8            // nodes per k1 wave   -> 256 chunks
#define K23_CHUNK 16          // nodes per k23 wave  -> 128 chunks

typedef __bf16 bf16x8 __attribute__((ext_vector_type(8)));
typedef float  f32x16 __attribute__((ext_vector_type(16)));

__device__ __forceinline__ unsigned short f2bf(float f) {
    unsigned int x = __float_as_uint(f);
    unsigned int lsb = (x >> 16) & 1u;
    x += 0x7fffu + lsb;                 // RNE
    return (unsigned short)(x >> 16);
}
__device__ __forceinline__ float bflo(unsigned int u) { return __uint_as_float(u << 16); }
__device__ __forceinline__ float bfhi(unsigned int u) { return __uint_as_float(u & 0xffff0000u); }

// ---------------- fast path ----------------

// x [b][n][i] fp32 -> xT [n][b][i] bf16
__global__ __launch_bounds__(256) void xt_kernel(const float* __restrict__ xg,
                                                 unsigned short* __restrict__ xT) {
    int id = blockIdx.x * 256 + threadIdx.x;      // 524288
    int b = id >> 13;
    int rem = id & 8191;
    int n = rem >> 2;
    int i4 = rem & 3;
    float4 v = *(const float4*)(xg + ((size_t)b * NN + n) * NI + i4 * 4);
    ushort4 o;
    o.x = f2bf(v.x); o.y = f2bf(v.y); o.z = f2bf(v.z); o.w = f2bf(v.w);
    *(ushort4*)(xT + ((size_t)n * BATCH + b) * NI + i4 * 4) = o;
}

// One wave per (chunk c of 8 nodes, capsule k): 8192 waves, 2048 blocks x 4.
// A = x-frag (A[m=b][kd=i]), B = W-frag (B[kd=i][col=o]) => D[m=b][col=o].
// Stores: scalar ushort per accumulator reg; lanes sweep o => 2 full 64B
// lines per instruction into priors[n][b][k][o]. Depth-1 prefetch.
__global__ __launch_bounds__(256) void k1_kernel(
    const unsigned short* __restrict__ xT,   // bf16 [n][b][i]
    const float* __restrict__ Wg,            // fp32 [n][k][i][o]
    unsigned short* __restrict__ priors,     // bf16 [n][b][k][o]
    float* __restrict__ partial)             // fp32 [256][b][k][o]
{
    const int w    = threadIdx.x >> 6;       // 0..3
    const int lane = threadIdx.x & 63;
    const int task = blockIdx.x * 4 + w;     // 8192 = 256 c x 32 k
    const int k  = task & 31;
    const int c  = task >> 5;                // 0..255
    const int l5 = lane & 31;                // o (B col); also x-row select
    const int h  = lane >> 5;
    const int base = c * K1_CHUNK;

    float s0a[16], s0b[16];
#pragma unroll
    for (int r = 0; r < 16; ++r) { s0a[r] = 0.f; s0b[r] = 0.f; }

    // prefetch node `base`
    float wf[8];
    bf16x8 x0n, x1n;
    {
        const float* wp = Wg + ((size_t)base * NK + k) * (NI * NO) + (h * 8) * NO + l5;
#pragma unroll
        for (int j = 0; j < 8; ++j) wf[j] = wp[j * NO];
        x0n = *(const bf16x8*)(xT + (size_t)base * (BATCH * NI) + l5 * NI + h * 8);
        x1n = *(const bf16x8*)(xT + (size_t)base * (BATCH * NI) + (l5 + 32) * NI + h * 8);
    }

    for (int jj = 0; jj < K1_CHUNK; ++jj) {
        const int n = base + jj;
        float wc[8];
#pragma unroll
        for (int j = 0; j < 8; ++j) wc[j] = wf[j];
        const bf16x8 x0c = x0n, x1c = x1n;

        if (jj < K1_CHUNK - 1) {
            const int n2 = n + 1;
            const float* wp = Wg + ((size_t)n2 * NK + k) * (NI * NO) + (h * 8) * NO + l5;
#pragma unroll
            for (int j = 0; j < 8; ++j) wf[j] = wp[j * NO];
            x0n = *(const bf16x8*)(xT + (size_t)n2 * (BATCH * NI) + l5 * NI + h * 8);
            x1n = *(const bf16x8*)(xT + (size_t)n2 * (BATCH * NI) + (l5 + 32) * NI + h * 8);
        }

        union { unsigned short u[8]; bf16x8 v; } bu;
#pragma unroll
        for (int j = 0; j < 8; ++j) bu.u[j] = f2bf(wc[j]);

        f32x16 c0, c1;
#pragma unroll
        for (int r = 0; r < 16; ++r) { c0[r] = 0.f; c1[r] = 0.f; }
        // A=x rows b (c0: b=0..31, c1: b=32..63), B=W cols o
        c0 = __builtin_amdgcn_mfma_f32_32x32x16_bf16(x0c, bu.v, c0, 0, 0, 0);
        c1 = __builtin_amdgcn_mfma_f32_32x32x16_bf16(x1c, bu.v, c1, 0, 0, 0);

        // priors index: n*65536 + b*1024 + k*32 + o
        unsigned short* pp = priors + (size_t)n * (BATCH * NK * NO) + k * NO + l5;
#pragma unroll
        for (int r = 0; r < 16; ++r) {
            const int b = (r & 3) + 8 * (r >> 2) + 4 * h;   // D row (m74/m101)
            pp[(size_t)b * (NK * NO)] = f2bf(c0[r]);
            pp[(size_t)(b + 32) * (NK * NO)] = f2bf(c1[r]);
            s0a[r] += c0[r];
            s0b[r] += c1[r];
        }
    }

    float* q = partial + (size_t)c * (BATCH * NK * NO) + k * NO + l5;
#pragma unroll
    for (int r = 0; r < 16; ++r) {
        const int b = (r & 3) + 8 * (r >> 2) + 4 * h;
        q[(size_t)b * (NK * NO)] = s0a[r] * (1.f / 32.f);
        q[(size_t)(b + 32) * (NK * NO)] = s0b[r] * (1.f / 32.f);
    }
}

// Iterations 1/2: one wave per (b, chunk of 16 nodes); 8192 waves.
// lane = k*2 + h(o-half). Per node: 32B/lane contiguous (2KB/wave).
// 4 nodes processed interleaved (4 independent chains through dot, exp,
// 5-hop softmax butterfly, div, accumulate); prefetch next 4-node group.
// Softmax without max-subtraction (|logits| <= ~8, exp safe in fp32).
template <int PASS>
__global__ __launch_bounds__(256) void k23_kernel(
    const unsigned short* __restrict__ priors,  // bf16 [n][b][k][o]
    const float* __restrict__ outv,             // fp32 [b][k][o]
    float* __restrict__ logits0,                // fp32 [n][b][k]
    float* __restrict__ partial)                // fp32 [128][b][k][o]
{
    const int wv   = threadIdx.x >> 6;
    const int lane = threadIdx.x & 63;
    const int task = blockIdx.x * 4 + wv;       // 8192 = 128 c x 64 b
    const int b = task & 63;
    const int c = task >> 6;                    // 0..127, 16 nodes each
    const int k = lane >> 1;
    const int h = lane & 1;

    float outr[16];
    {
        const float4* op = (const float4*)(outv + ((size_t)b * NK + k) * NO + h * 16);
#pragma unroll
        for (int q = 0; q < 4; ++q) {
            float4 v = op[q];
            outr[4*q+0] = v.x; outr[4*q+1] = v.y; outr[4*q+2] = v.z; outr[4*q+3] = v.w;
        }
    }

    float sa[16];
#pragma unroll
    for (int m = 0; m < 16; ++m) sa[m] = 0.f;

    // node stride in uint4: 64*32*32 ushorts / 8 = 8192
    const uint4* p = (const uint4*)(priors +
        (((size_t)(c * K23_CHUNK) * BATCH + b) * NK + k) * NO + h * 16);
    float* lg = logits0 + ((size_t)(c * K23_CHUNK) * BATCH + b) * NK + k;  // node stride 2048 floats

    union Q { uint4 q[2]; unsigned u[8]; };
    Q cur[4], nxt[4];
    float gl[4], gn[4];

#pragma unroll
    for (int j = 0; j < 4; ++j) {
        cur[j].q[0] = p[(size_t)j * 8192];
        cur[j].q[1] = p[(size_t)j * 8192 + 1];
    }
    if constexpr (PASS == 2) {
#pragma unroll
        for (int j = 0; j < 4; ++j) gl[j] = lg[(size_t)j * 2048];
    }

#pragma unroll
    for (int g = 0; g < K23_CHUNK / 4; ++g) {
        if (g < K23_CHUNK / 4 - 1) {
#pragma unroll
            for (int j = 0; j < 4; ++j) {
                const size_t nj = (size_t)((g + 1) * 4 + j);
                nxt[j].q[0] = p[nj * 8192];
                nxt[j].q[1] = p[nj * 8192 + 1];
            }
            if constexpr (PASS == 2) {
#pragma unroll
                for (int j = 0; j < 4; ++j) gn[j] = lg[(size_t)((g + 1) * 4 + j) * 2048];
            }
        }

        // 4 interleaved dot products over 16 o-elements
        float d0 = 0.f, d1 = 0.f, d2 = 0.f, d3 = 0.f;
#pragma unroll
        for (int m = 0; m < 8; ++m) {
            d0 = fmaf(bflo(cur[0].u[m]), outr[2*m], d0);
            d1 = fmaf(bflo(cur[1].u[m]), outr[2*m], d1);
            d2 = fmaf(bflo(cur[2].u[m]), outr[2*m], d2);
            d3 = fmaf(bflo(cur[3].u[m]), outr[2*m], d3);
            d0 = fmaf(bfhi(cur[0].u[m]), outr[2*m+1], d0);
            d1 = fmaf(bfhi(cur[1].u[m]), outr[2*m+1], d1);
            d2 = fmaf(bfhi(cur[2].u[m]), outr[2*m+1], d2);
            d3 = fmaf(bfhi(cur[3].u[m]), outr[2*m+1], d3);
        }
        d0 += __shfl_xor(d0, 1);
        d1 += __shfl_xor(d1, 1);
        d2 += __shfl_xor(d2, 1);
        d3 += __shfl_xor(d3, 1);

        float l0, l1, l2, l3;
        if constexpr (PASS == 1) {
            l0 = d0; l1 = d1; l2 = d2; l3 = d3;
            if (h == 0) {
                lg[(size_t)(g * 4 + 0) * 2048] = d0;   // 32 lanes -> 128B contiguous
                lg[(size_t)(g * 4 + 1) * 2048] = d1;
                lg[(size_t)(g * 4 + 2) * 2048] = d2;
                lg[(size_t)(g * 4 + 3) * 2048] = d3;
            }
        } else {
            l0 = gl[0] + d0; l1 = gl[1] + d1; l2 = gl[2] + d2; l3 = gl[3] + d3;
        }

        float e0 = __expf(l0), e1 = __expf(l1), e2 = __expf(l2), e3 = __expf(l3);
        float s0 = e0, s1 = e1, s2 = e2, s3 = e3;
#pragma unroll
        for (int mask = 2; mask < 64; mask <<= 1) {
            s0 += __shfl_xor(s0, mask);
            s1 += __shfl_xor(s1, mask);
            s2 += __shfl_xor(s2, mask);
            s3 += __shfl_xor(s3, mask);
        }
        const float p0 = e0 / s0, p1 = e1 / s1, p2 = e2 / s2, p3 = e3 / s3;

#pragma unroll
        for (int m = 0; m < 8; ++m) {
            sa[2*m]   = fmaf(p0, bflo(cur[0].u[m]), sa[2*m]);
            sa[2*m]   = fmaf(p1, bflo(cur[1].u[m]), sa[2*m]);
            sa[2*m]   = fmaf(p2, bflo(cur[2].u[m]), sa[2*m]);
            sa[2*m]   = fmaf(p3, bflo(cur[3].u[m]), sa[2*m]);
            sa[2*m+1] = fmaf(p0, bfhi(cur[0].u[m]), sa[2*m+1]);
            sa[2*m+1] = fmaf(p1, bfhi(cur[1].u[m]), sa[2*m+1]);
            sa[2*m+1] = fmaf(p2, bfhi(cur[2].u[m]), sa[2*m+1]);
            sa[2*m+1] = fmaf(p3, bfhi(cur[3].u[m]), sa[2*m+1]);
        }

#pragma unroll
        for (int j = 0; j < 4; ++j) cur[j] = nxt[j];
        if constexpr (PASS == 2) {
#pragma unroll
            for (int j = 0; j < 4; ++j) gl[j] = gn[j];
        }
    }

    float* wq = partial + (((size_t)c * BATCH + b) * NK + k) * NO + h * 16;
#pragma unroll
    for (int q = 0; q < 4; ++q)
        *(float4*)(wq + 4 * q) = make_float4(sa[4*q], sa[4*q+1], sa[4*q+2], sa[4*q+3]);
}

// Reduce partial chunks + squash. tid = b*1024 + k*32 + o.
template <int NCH>
__global__ __launch_bounds__(256) void reduce_squash_f(
    const float* __restrict__ partial,
    float* __restrict__ outf)
{
    const int tid = blockIdx.x * 256 + threadIdx.x;
    float v = 0.f;
    for (int cix = 0; cix < NCH; ++cix)
        v += partial[(size_t)cix * (BATCH * NK * NO) + tid];
    float sq = v * v;
#pragma unroll
    for (int off = 1; off < 32; off <<= 1)
        sq += __shfl_xor(sq, off);
    float coef = sq / ((1.f + sq) * sqrtf(sq));
    outf[tid] = v * coef;
}

// ---------------- legacy fallback (round-2 code, known-good 582 us) ----------------

#define LBB 32
#define LNCHUNK 8
#define LNBLK (NN / LNCHUNK)
#define LTHREADS 512
#define WK_STRIDE 516

template <int PASS>
__global__ __launch_bounds__(LTHREADS, 1) void legacy_pass(
    const float* __restrict__ xg, const float* __restrict__ Wg,
    const float* __restrict__ outv, float* __restrict__ logits,
    float* __restrict__ partial)
{
    __shared__ float w_lds[NK * WK_STRIDE];
    __shared__ float x_lds[LBB][NI + 1];
    __shared__ float delta_lds[LBB][NK + 1];
    const int t = threadIdx.x, nb = blockIdx.x, bg = blockIdx.y;
    const int b0 = bg * LBB;
    const int k = t >> 4, bq = t & 15, bl0 = bq * 2, bl1 = bq * 2 + 1;
    float acc0[NO], acc1[NO];
#pragma unroll
    for (int o = 0; o < NO; ++o) { acc0[o] = 0.f; acc1[o] = 0.f; }
    float outr0[NO], outr1[NO];
    if constexpr (PASS >= 1) {
        const float4* o0 = (const float4*)&outv[((b0 + bl0) * NK + k) * NO];
        const float4* o1 = (const float4*)&outv[((b0 + bl1) * NK + k) * NO];
#pragma unroll
        for (int q = 0; q < NO / 4; ++q) {
            float4 a = o0[q]; float4 b = o1[q];
            outr0[4*q+0]=a.x; outr0[4*q+1]=a.y; outr0[4*q+2]=a.z; outr0[4*q+3]=a.w;
            outr1[4*q+0]=b.x; outr1[4*q+1]=b.y; outr1[4*q+2]=b.z; outr1[4*q+3]=b.w;
        }
    }
    for (int j = 0; j < LNCHUNK; ++j) {
        const int n = nb * LNCHUNK + j;
        __syncthreads();
        {
            const float4* src = (const float4*)(Wg + (size_t)n * (NK * NI * NO));
#pragma unroll
            for (int r = 0; r < (NK * NI * NO / 4) / LTHREADS; ++r) {
                int idx4 = t + r * LTHREADS;
                float4 v = src[idx4];
                int e = idx4 * 4, kk = e >> 9, rem = e & 511;
                *(float4*)&w_lds[kk * WK_STRIDE + rem] = v;
            }
        }
        { int bl = t >> 4, i = t & 15;
          x_lds[bl][i] = xg[((size_t)(b0 + bl) * NN + n) * NI + i]; }
        __syncthreads();
        if constexpr (PASS == 0) {
#pragma unroll
            for (int i = 0; i < NI; ++i) {
                float xa = x_lds[bl0][i], xb = x_lds[bl1][i];
                const float* wrow = &w_lds[k * WK_STRIDE + i * NO];
#pragma unroll
                for (int o = 0; o < NO; ++o) {
                    float w = wrow[o];
                    acc0[o] = fmaf(xa, w, acc0[o]);
                    acc1[o] = fmaf(xb, w, acc1[o]);
                }
            }
        } else {
            float pr0[NO], pr1[NO];
#pragma unroll
            for (int o = 0; o < NO; ++o) { pr0[o] = 0.f; pr1[o] = 0.f; }
#pragma unroll
            for (int i = 0; i < NI; ++i) {
                float xa = x_lds[bl0][i], xb = x_lds[bl1][i];
                const float* wrow = &w_lds[k * WK_STRIDE + i * NO];
#pragma unroll
                for (int o = 0; o < NO; ++o) {
                    float w = wrow[o];
                    pr0[o] = fmaf(xa, w, pr0[o]);
                    pr1[o] = fmaf(xb, w, pr1[o]);
                }
            }
            float d0 = 0.f, d1 = 0.f;
#pragma unroll
            for (int o = 0; o < NO; ++o) {
                d0 = fmaf(pr0[o], outr0[o], d0);
                d1 = fmaf(pr1[o], outr1[o], d1);
            }
            float l0 = d0, l1 = d1;
            const size_t li0 = ((size_t)(b0 + bl0) * NN + n) * NK + k;
            const size_t li1 = ((size_t)(b0 + bl1) * NN + n) * NK + k;
            if constexpr (PASS == 2) { l0 += logits[li0]; l1 += logits[li1]; }
            else { logits[li0] = d0; logits[li1] = d1; }
            delta_lds[bl0][k] = l0; delta_lds[bl1][k] = l1;
            __syncthreads();
            float m0 = -1e30f, m1 = -1e30f;
#pragma unroll
            for (int kk = 0; kk < NK; ++kk) {
                m0 = fmaxf(m0, delta_lds[bl0][kk]);
                m1 = fmaxf(m1, delta_lds[bl1][kk]);
            }
            float s0 = 0.f, s1 = 0.f;
#pragma unroll
            for (int kk = 0; kk < NK; ++kk) {
                s0 += __expf(delta_lds[bl0][kk] - m0);
                s1 += __expf(delta_lds[bl1][kk] - m1);
            }
            float p0 = __expf(l0 - m0) / s0;
            float p1 = __expf(l1 - m1) / s1;
#pragma unroll
            for (int o = 0; o < NO; ++o) {
                acc0[o] = fmaf(p0, pr0[o], acc0[o]);
                acc1[o] = fmaf(p1, pr1[o], acc1[o]);
            }
        }
    }
    const float scale = (PASS == 0) ? (1.f / NK) : 1.f;
    float4* p0 = (float4*)&partial[(((size_t)nb * BATCH + (b0 + bl0)) * NK + k) * NO];
    float4* p1 = (float4*)&partial[(((size_t)nb * BATCH + (b0 + bl1)) * NK + k) * NO];
#pragma unroll
    for (int q = 0; q < NO / 4; ++q) {
        float4 v0, v1;
        v0.x = acc0[4*q+0]*scale; v0.y = acc0[4*q+1]*scale;
        v0.z = acc0[4*q+2]*scale; v0.w = acc0[4*q+3]*scale;
        v1.x = acc1[4*q+0]*scale; v1.y = acc1[4*q+1]*scale;
        v1.z = acc1[4*q+2]*scale; v1.w = acc1[4*q+3]*scale;
        p0[q] = v0; p1[q] = v1;
    }
}

__global__ __launch_bounds__(256) void legacy_reduce(
    const float* __restrict__ partial, float* __restrict__ outf)
{
    const int tid = blockIdx.x * 256 + threadIdx.x;
    float v = 0.f;
    for (int nb = 0; nb < LNBLK; ++nb)
        v += partial[(size_t)nb * (BATCH * NK * NO) + tid];
    float sq = v * v;
#pragma unroll
    for (int off = 1; off < 32; off <<= 1) sq += __shfl_xor(sq, off);
    float coef = sq / ((1.f + sq) * sqrtf(sq));
    outf[tid] = v * coef;
}

// ---------------- launch ----------------

extern "C" void kernel_launch(void* const* d_in, const int* in_sizes, int n_in,
                              void* d_out, int out_size, void* d_ws, size_t ws_size,
                              hipStream_t stream)
{
    const float* xg = (const float*)d_in[0];
    const float* Wg = (const float*)d_in[1];
    float* outp = (float*)d_out;
    char* ws = (char*)d_ws;

    const size_t SZ_PRIORS  = (size_t)NN * BATCH * NK * NO * 2;      // 256 MiB
    const size_t SZ_PARTIAL = (size_t)256 * BATCH * NK * NO * 4;     //  64 MiB
    const size_t SZ_LOGITS  = (size_t)NN * BATCH * NK * 4;           //  16 MiB
    const size_t SZ_XT      = (size_t)NN * BATCH * NI * 2;           //   4 MiB
    const size_t SZ_OUTV    = (size_t)BATCH * NK * NO * 4;           // 256 KiB
    const size_t NEED = SZ_PRIORS + SZ_PARTIAL + SZ_LOGITS + SZ_XT + SZ_OUTV;

    if (ws_size >= NEED) {
        unsigned short* priors = (unsigned short*)ws;
        float* partial = (float*)(ws + SZ_PRIORS);
        float* logits0 = (float*)(ws + SZ_PRIORS + SZ_PARTIAL);
        unsigned short* xT = (unsigned short*)(ws + SZ_PRIORS + SZ_PARTIAL + SZ_LOGITS);
        float* outv = (float*)(ws + SZ_PRIORS + SZ_PARTIAL + SZ_LOGITS + SZ_XT);

        xt_kernel<<<2048, 256, 0, stream>>>(xg, xT);
        k1_kernel<<<2048, 256, 0, stream>>>(xT, Wg, priors, partial);
        reduce_squash_f<256><<<256, 256, 0, stream>>>(partial, outv);
        k23_kernel<1><<<2048, 256, 0, stream>>>(priors, outv, logits0, partial);
        reduce_squash_f<128><<<256, 256, 0, stream>>>(partial, outv);
        k23_kernel<2><<<2048, 256, 0, stream>>>(priors, outv, logits0, partial);
        reduce_squash_f<128><<<256, 256, 0, stream>>>(partial, outp);
    } else {
        float* partial = (float*)ws;
        float* logits = (float*)(ws + (size_t)LNBLK * BATCH * NK * NO * 4);
        float* outv = (float*)(ws + (size_t)LNBLK * BATCH * NK * NO * 4 + (size_t)BATCH * NN * NK * 4);
        dim3 grid(LNBLK, BATCH / LBB);
        const int rblocks = BATCH * NK * NO / 256;
        legacy_pass<0><<<grid, LTHREADS, 0, stream>>>(xg, Wg, nullptr, logits, partial);
        legacy_reduce<<<rblocks, 256, 0, stream>>>(partial, outv);
        legacy_pass<1><<<grid, LTHREADS, 0, stream>>>(xg, Wg, outv, logits, partial);
        legacy_reduce<<<rblocks, 256, 0, stream>>>(partial, outv);
        legacy_pass<2><<<grid, LTHREADS, 0, stream>>>(xg, Wg, outv, logits, partial);
        legacy_reduce<<<rblocks, 256, 0, stream>>>(partial, outp);
    }
}

// Round 9
// 445.824 us; speedup vs baseline: 1.0667x; 1.0667x over previous
//
#include <hip/hip_runtime.h>
#include <math.h>

// CapsuleLayer routing on MI355X (gfx950). fp32 in/out.
// B=64, n=2048, k=32, in_C=16, out_C=32, 3 routing iterations.
//
// Round-9 restructure: NO priors array. W is transpose-converted once to
// bf16 wq[n][k][o][i] (64 MB, L3-resident). Each iteration is one fused
// kernel: per node, MFMA recomputes priors into C regs (A=x[32b x 16i],
// B=wq[16i x 32o]) -> LDS round-trip (C-layout -> routing layout, padded
// stride vs bank conflicts) -> in-wave shuffle softmax (k in lanes, no
// max-subtraction) -> accumulate s. Kills the 768 MB priors HBM round-trip
// that pinned rounds 4-8 at ~430-480 us (k1 128 us write-bound + 2x k23
// ~149 us read-bound).

#define BATCH 64
#define NN    2048
#define NK    32
#define NI    16
#define NO    32

#define PNB   16                  // nodes per fused block
#define NSETS (NN / PNB)          // 128 node-sets
#define PS    1080                // ushort stride per b-row in LDS (1024 + 56 pad)

typedef __bf16 bf16x8 __attribute__((ext_vector_type(8)));
typedef float  f32x16 __attribute__((ext_vector_type(16)));

__device__ __forceinline__ unsigned short f2bf(float f) {
    unsigned int x = __float_as_uint(f);
    unsigned int lsb = (x >> 16) & 1u;
    x += 0x7fffu + lsb;                 // RNE
    return (unsigned short)(x >> 16);
}
__device__ __forceinline__ float bflo(unsigned int u) { return __uint_as_float(u << 16); }
__device__ __forceinline__ float bfhi(unsigned int u) { return __uint_as_float(u & 0xffff0000u); }

// ---------------- fast path ----------------

// x [b][n][i] fp32 -> xT [n][b][i] bf16
__global__ __launch_bounds__(256) void xt_kernel(const float* __restrict__ xg,
                                                 unsigned short* __restrict__ xT) {
    int id = blockIdx.x * 256 + threadIdx.x;      // 524288
    int b = id >> 13;
    int rem = id & 8191;
    int n = rem >> 2;
    int i4 = rem & 3;
    float4 v = *(const float4*)(xg + ((size_t)b * NN + n) * NI + i4 * 4);
    ushort4 o;
    o.x = f2bf(v.x); o.y = f2bf(v.y); o.z = f2bf(v.z); o.w = f2bf(v.w);
    *(ushort4*)(xT + ((size_t)n * BATCH + b) * NI + i4 * 4) = o;
}

// W fp32 [n][k][i][o] -> wq bf16 [n][k][o][i]  (B-fragment-ready: lane=o
// reads 8 consecutive i = 16B). One wave per (n,k) slice; reads coalesced
// (fixed i: 32 lanes x 4B contiguous), writes 2KB contiguous per wave.
__global__ __launch_bounds__(256) void wqt_kernel(const float* __restrict__ Wg,
                                                  unsigned short* __restrict__ wq) {
    const int w    = threadIdx.x >> 6;
    const int lane = threadIdx.x & 63;
    const int task = blockIdx.x * 4 + w;          // 65536 = n*32 + k
    const int o  = lane & 31;
    const int ih = lane >> 5;                     // i-half
    const float* src = Wg + (size_t)task * (NI * NO);
    unsigned short d[8];
#pragma unroll
    for (int j = 0; j < 8; ++j)
        d[j] = f2bf(src[(ih * 8 + j) * NO + o]);
    *(uint4*)(wq + (size_t)task * (NO * NI) + o * NI + ih * 8) = *(uint4*)d;
}

// Fused routing pass. Grid (128 sets, 2 b-halves), block 1024 thr = 16 waves.
// Wave w: MFMA tiles k0=2w,k1=2w+1 (A = xT rows b of this half, B = wq);
// routing rows b_l = 2w, 2w+1 (lane = k*2 + h over 32 k x 2 o-halves).
// Per node: mfma -> barrier -> C regs to LDS (bf16, padded rows) -> barrier
// -> routing reads 32B/lane, delta dot, shfl-pair, 5-hop softmax, accum.
// PASS 0: uniform probs (sa += f, scale 1/32; no logits/out).
template <int PASS>
__global__ __launch_bounds__(1024) void fused_pass(
    const unsigned short* __restrict__ xT,   // bf16 [n][b][i]
    const unsigned short* __restrict__ wq,   // bf16 [n][k][o][i]
    const float* __restrict__ outv,          // fp32 [b][k][o]   (PASS>=1)
    float* __restrict__ logits0,             // fp32 [n][b][k]   (PASS>=1)
    float* __restrict__ partial)             // fp32 [128][64][32][32]
{
    __shared__ unsigned short plds[32 * PS];     // 69120 B

    const int w    = threadIdx.x >> 6;           // 0..15
    const int lane = threadIdx.x & 63;
    const int set  = blockIdx.x;                 // 0..127
    const int hb   = blockIdx.y;                 // b-half
    const int l5   = lane & 31;
    const int h5   = lane >> 5;
    const int k0   = 2 * w, k1 = 2 * w + 1;
    const int kl   = lane >> 1;                  // routing k
    const int hl   = lane & 1;                   // routing o-half
    const int bl0  = 2 * w, bl1 = 2 * w + 1;     // routing rows (local)
    const int bg0  = hb * 32 + bl0, bg1 = hb * 32 + bl1;
    const int nbase = set * PNB;

    float o0[16], o1[16];
    if constexpr (PASS >= 1) {
        const float* p0 = outv + (size_t)bg0 * (NK * NO) + kl * NO + hl * 16;
        const float* p1 = outv + (size_t)bg1 * (NK * NO) + kl * NO + hl * 16;
#pragma unroll
        for (int q = 0; q < 4; ++q) {
            float4 a = *(const float4*)(p0 + 4 * q);
            float4 b = *(const float4*)(p1 + 4 * q);
            o0[4*q+0]=a.x; o0[4*q+1]=a.y; o0[4*q+2]=a.z; o0[4*q+3]=a.w;
            o1[4*q+0]=b.x; o1[4*q+1]=b.y; o1[4*q+2]=b.z; o1[4*q+3]=b.w;
        }
    }

    float sa0[16], sa1[16];
#pragma unroll
    for (int m = 0; m < 16; ++m) { sa0[m] = 0.f; sa1[m] = 0.f; }

    // fragment prefetch (depth 1)
    bf16x8 aN, b0N, b1N;
    float lgN0 = 0.f, lgN1 = 0.f;
    {
        const int n = nbase;
        aN  = *(const bf16x8*)(xT + (size_t)n * (BATCH * NI) + (hb * 32 + l5) * NI + h5 * 8);
        b0N = *(const bf16x8*)(wq + (size_t)n * (NK * NO * NI) + k0 * (NO * NI) + l5 * NI + h5 * 8);
        b1N = *(const bf16x8*)(wq + (size_t)n * (NK * NO * NI) + k1 * (NO * NI) + l5 * NI + h5 * 8);
        if constexpr (PASS == 2) {
            lgN0 = logits0[(size_t)n * (BATCH * NK) + bg0 * NK + kl];
            lgN1 = logits0[(size_t)n * (BATCH * NK) + bg1 * NK + kl];
        }
    }

    for (int j = 0; j < PNB; ++j) {
        const int n = nbase + j;
        const bf16x8 aC = aN, b0C = b0N, b1C = b1N;
        const float lgC0 = lgN0, lgC1 = lgN1;
        if (j < PNB - 1) {
            const int n2 = n + 1;
            aN  = *(const bf16x8*)(xT + (size_t)n2 * (BATCH * NI) + (hb * 32 + l5) * NI + h5 * 8);
            b0N = *(const bf16x8*)(wq + (size_t)n2 * (NK * NO * NI) + k0 * (NO * NI) + l5 * NI + h5 * 8);
            b1N = *(const bf16x8*)(wq + (size_t)n2 * (NK * NO * NI) + k1 * (NO * NI) + l5 * NI + h5 * 8);
            if constexpr (PASS == 2) {
                lgN0 = logits0[(size_t)n2 * (BATCH * NK) + bg0 * NK + kl];
                lgN1 = logits0[(size_t)n2 * (BATCH * NK) + bg1 * NK + kl];
            }
        }

        f32x16 c0, c1;
#pragma unroll
        for (int r = 0; r < 16; ++r) { c0[r] = 0.f; c1[r] = 0.f; }
        c0 = __builtin_amdgcn_mfma_f32_32x32x16_bf16(aC, b0C, c0, 0, 0, 0);
        c1 = __builtin_amdgcn_mfma_f32_32x32x16_bf16(aC, b1C, c1, 0, 0, 0);

        __syncthreads();   // previous node's routing reads complete
#pragma unroll
        for (int r = 0; r < 16; ++r) {
            const int bL = (r & 3) + 8 * (r >> 2) + 4 * h5;   // C/D row (m74/m101)
            unsigned short* row = plds + bL * PS;
            row[k0 * 32 + l5] = f2bf(c0[r]);
            row[k1 * 32 + l5] = f2bf(c1[r]);
        }
        __syncthreads();

        // ---- routing for the wave's two b rows ----
#pragma unroll
        for (int rr = 0; rr < 2; ++rr) {
            const int b_l = rr ? bl1 : bl0;
            const int bg  = rr ? bg1 : bg0;
            float* sa = rr ? sa1 : sa0;
            const float* outr = rr ? o1 : o0;
            const float lgC = rr ? lgC1 : lgC0;

            const uint4* pl = (const uint4*)(plds + b_l * PS + kl * 32 + hl * 16);
            uint4 u0 = pl[0], u1 = pl[1];
            float f[16];
            f[0]=bflo(u0.x); f[1]=bfhi(u0.x); f[2]=bflo(u0.y); f[3]=bfhi(u0.y);
            f[4]=bflo(u0.z); f[5]=bfhi(u0.z); f[6]=bflo(u0.w); f[7]=bfhi(u0.w);
            f[8]=bflo(u1.x); f[9]=bfhi(u1.x); f[10]=bflo(u1.y); f[11]=bfhi(u1.y);
            f[12]=bflo(u1.z); f[13]=bfhi(u1.z); f[14]=bflo(u1.w); f[15]=bfhi(u1.w);

            if constexpr (PASS == 0) {
#pragma unroll
                for (int m = 0; m < 16; ++m) sa[m] += f[m];
            } else {
                float d = 0.f;
#pragma unroll
                for (int m = 0; m < 16; ++m) d = fmaf(f[m], outr[m], d);
                d += __shfl_xor(d, 1);
                float l;
                if constexpr (PASS == 1) {
                    l = d;
                    if (hl == 0)
                        logits0[(size_t)n * (BATCH * NK) + bg * NK + kl] = d;
                } else {
                    l = lgC + d;
                }
                // softmax over k, no max-subtraction (|l| <= ~8, fp32-safe)
                float e = __expf(l);
                float s = e;
#pragma unroll
                for (int mask = 2; mask < 64; mask <<= 1)
                    s += __shfl_xor(s, mask);
                const float pr = e / s;
#pragma unroll
                for (int m = 0; m < 16; ++m) sa[m] = fmaf(pr, f[m], sa[m]);
            }
        }
    }

    const float scale = (PASS == 0) ? (1.f / NK) : 1.f;
    float* pw0 = partial + ((size_t)set * BATCH + bg0) * (NK * NO) + kl * NO + hl * 16;
    float* pw1 = partial + ((size_t)set * BATCH + bg1) * (NK * NO) + kl * NO + hl * 16;
#pragma unroll
    for (int q = 0; q < 4; ++q) {
        *(float4*)(pw0 + 4 * q) = make_float4(sa0[4*q] * scale, sa0[4*q+1] * scale,
                                              sa0[4*q+2] * scale, sa0[4*q+3] * scale);
        *(float4*)(pw1 + 4 * q) = make_float4(sa1[4*q] * scale, sa1[4*q+1] * scale,
                                              sa1[4*q+2] * scale, sa1[4*q+3] * scale);
    }
}

// Reduce partial chunks + squash. tid = b*1024 + k*32 + o.
template <int NCH>
__global__ __launch_bounds__(256) void reduce_squash_f(
    const float* __restrict__ partial,
    float* __restrict__ outf)
{
    const int tid = blockIdx.x * 256 + threadIdx.x;
    float v = 0.f;
    for (int cix = 0; cix < NCH; ++cix)
        v += partial[(size_t)cix * (BATCH * NK * NO) + tid];
    float sq = v * v;
#pragma unroll
    for (int off = 1; off < 32; off <<= 1)
        sq += __shfl_xor(sq, off);
    float coef = sq / ((1.f + sq) * sqrtf(sq));
    outf[tid] = v * coef;
}

// ---------------- legacy fallback (round-2 code, known-good 582 us) ----------------

#define LBB 32
#define LNCHUNK 8
#define LNBLK (NN / LNCHUNK)
#define LTHREADS 512
#define WK_STRIDE 516

template <int PASS>
__global__ __launch_bounds__(LTHREADS, 1) void legacy_pass(
    const float* __restrict__ xg, const float* __restrict__ Wg,
    const float* __restrict__ outv, float* __restrict__ logits,
    float* __restrict__ partial)
{
    __shared__ float w_lds[NK * WK_STRIDE];
    __shared__ float x_lds[LBB][NI + 1];
    __shared__ float delta_lds[LBB][NK + 1];
    const int t = threadIdx.x, nb = blockIdx.x, bg = blockIdx.y;
    const int b0 = bg * LBB;
    const int k = t >> 4, bq = t & 15, bl0 = bq * 2, bl1 = bq * 2 + 1;
    float acc0[NO], acc1[NO];
#pragma unroll
    for (int o = 0; o < NO; ++o) { acc0[o] = 0.f; acc1[o] = 0.f; }
    float outr0[NO], outr1[NO];
    if constexpr (PASS >= 1) {
        const float4* o0 = (const float4*)&outv[((b0 + bl0) * NK + k) * NO];
        const float4* o1 = (const float4*)&outv[((b0 + bl1) * NK + k) * NO];
#pragma unroll
        for (int q = 0; q < NO / 4; ++q) {
            float4 a = o0[q]; float4 b = o1[q];
            outr0[4*q+0]=a.x; outr0[4*q+1]=a.y; outr0[4*q+2]=a.z; outr0[4*q+3]=a.w;
            outr1[4*q+0]=b.x; outr1[4*q+1]=b.y; outr1[4*q+2]=b.z; outr1[4*q+3]=b.w;
        }
    }
    for (int j = 0; j < LNCHUNK; ++j) {
        const int n = nb * LNCHUNK + j;
        __syncthreads();
        {
            const float4* src = (const float4*)(Wg + (size_t)n * (NK * NI * NO));
#pragma unroll
            for (int r = 0; r < (NK * NI * NO / 4) / LTHREADS; ++r) {
                int idx4 = t + r * LTHREADS;
                float4 v = src[idx4];
                int e = idx4 * 4, kk = e >> 9, rem = e & 511;
                *(float4*)&w_lds[kk * WK_STRIDE + rem] = v;
            }
        }
        { int bl = t >> 4, i = t & 15;
          x_lds[bl][i] = xg[((size_t)(b0 + bl) * NN + n) * NI + i]; }
        __syncthreads();
        if constexpr (PASS == 0) {
#pragma unroll
            for (int i = 0; i < NI; ++i) {
                float xa = x_lds[bl0][i], xb = x_lds[bl1][i];
                const float* wrow = &w_lds[k * WK_STRIDE + i * NO];
#pragma unroll
                for (int o = 0; o < NO; ++o) {
                    float w = wrow[o];
                    acc0[o] = fmaf(xa, w, acc0[o]);
                    acc1[o] = fmaf(xb, w, acc1[o]);
                }
            }
        } else {
            float pr0[NO], pr1[NO];
#pragma unroll
            for (int o = 0; o < NO; ++o) { pr0[o] = 0.f; pr1[o] = 0.f; }
#pragma unroll
            for (int i = 0; i < NI; ++i) {
                float xa = x_lds[bl0][i], xb = x_lds[bl1][i];
                const float* wrow = &w_lds[k * WK_STRIDE + i * NO];
#pragma unroll
                for (int o = 0; o < NO; ++o) {
                    float w = wrow[o];
                    pr0[o] = fmaf(xa, w, pr0[o]);
                    pr1[o] = fmaf(xb, w, pr1[o]);
                }
            }
            float d0 = 0.f, d1 = 0.f;
#pragma unroll
            for (int o = 0; o < NO; ++o) {
                d0 = fmaf(pr0[o], outr0[o], d0);
                d1 = fmaf(pr1[o], outr1[o], d1);
            }
            float l0 = d0, l1 = d1;
            const size_t li0 = ((size_t)(b0 + bl0) * NN + n) * NK + k;
            const size_t li1 = ((size_t)(b0 + bl1) * NN + n) * NK + k;
            if constexpr (PASS == 2) { l0 += logits[li0]; l1 += logits[li1]; }
            else { logits[li0] = d0; logits[li1] = d1; }
            delta_lds[bl0][k] = l0; delta_lds[bl1][k] = l1;
            __syncthreads();
            float m0 = -1e30f, m1 = -1e30f;
#pragma unroll
            for (int kk = 0; kk < NK; ++kk) {
                m0 = fmaxf(m0, delta_lds[bl0][kk]);
                m1 = fmaxf(m1, delta_lds[bl1][kk]);
            }
            float s0 = 0.f, s1 = 0.f;
#pragma unroll
            for (int kk = 0; kk < NK; ++kk) {
                s0 += __expf(delta_lds[bl0][kk] - m0);
                s1 += __expf(delta_lds[bl1][kk] - m1);
            }
            float p0 = __expf(l0 - m0) / s0;
            float p1 = __expf(l1 - m1) / s1;
#pragma unroll
            for (int o = 0; o < NO; ++o) {
                acc0[o] = fmaf(p0, pr0[o], acc0[o]);
                acc1[o] = fmaf(p1, pr1[o], acc1[o]);
            }
        }
    }
    const float scale = (PASS == 0) ? (1.f / NK) : 1.f;
    float4* p0 = (float4*)&partial[(((size_t)nb * BATCH + (b0 + bl0)) * NK + k) * NO];
    float4* p1 = (float4*)&partial[(((size_t)nb * BATCH + (b0 + bl1)) * NK + k) * NO];
#pragma unroll
    for (int q = 0; q < NO / 4; ++q) {
        float4 v0, v1;
        v0.x = acc0[4*q+0]*scale; v0.y = acc0[4*q+1]*scale;
        v0.z = acc0[4*q+2]*scale; v0.w = acc0[4*q+3]*scale;
        v1.x = acc1[4*q+0]*scale; v1.y = acc1[4*q+1]*scale;
        v1.z = acc1[4*q+2]*scale; v1.w = acc1[4*q+3]*scale;
        p0[q] = v0; p1[q] = v1;
    }
}

__global__ __launch_bounds__(256) void legacy_reduce(
    const float* __restrict__ partial, float* __restrict__ outf)
{
    const int tid = blockIdx.x * 256 + threadIdx.x;
    float v = 0.f;
    for (int nb = 0; nb < LNBLK; ++nb)
        v += partial[(size_t)nb * (BATCH * NK * NO) + tid];
    float sq = v * v;
#pragma unroll
    for (int off = 1; off < 32; off <<= 1) sq += __shfl_xor(sq, off);
    float coef = sq / ((1.f + sq) * sqrtf(sq));
    outf[tid] = v * coef;
}

// ---------------- launch ----------------

extern "C" void kernel_launch(void* const* d_in, const int* in_sizes, int n_in,
                              void* d_out, int out_size, void* d_ws, size_t ws_size,
                              hipStream_t stream)
{
    const float* xg = (const float*)d_in[0];
    const float* Wg = (const float*)d_in[1];
    float* outp = (float*)d_out;
    char* ws = (char*)d_ws;

    const size_t SZ_WQ      = (size_t)NN * NK * NO * NI * 2;         //  64 MiB
    const size_t SZ_XT      = (size_t)NN * BATCH * NI * 2;           //   4 MiB
    const size_t SZ_LOGITS  = (size_t)NN * BATCH * NK * 4;           //  16 MiB
    const size_t SZ_PARTIAL = (size_t)NSETS * BATCH * NK * NO * 4;   //  32 MiB
    const size_t SZ_OUTV    = (size_t)BATCH * NK * NO * 4;           // 256 KiB
    const size_t NEED = SZ_WQ + SZ_XT + SZ_LOGITS + SZ_PARTIAL + SZ_OUTV;

    if (ws_size >= NEED) {
        unsigned short* wq = (unsigned short*)ws;
        unsigned short* xT = (unsigned short*)(ws + SZ_WQ);
        float* logits0 = (float*)(ws + SZ_WQ + SZ_XT);
        float* partial = (float*)(ws + SZ_WQ + SZ_XT + SZ_LOGITS);
        float* outv    = (float*)(ws + SZ_WQ + SZ_XT + SZ_LOGITS + SZ_PARTIAL);

        xt_kernel<<<2048, 256, 0, stream>>>(xg, xT);
        wqt_kernel<<<16384, 256, 0, stream>>>(Wg, wq);

        dim3 pg(NSETS, 2);
        fused_pass<0><<<pg, 1024, 0, stream>>>(xT, wq, nullptr, nullptr, partial);
        reduce_squash_f<NSETS><<<256, 256, 0, stream>>>(partial, outv);
        fused_pass<1><<<pg, 1024, 0, stream>>>(xT, wq, outv, logits0, partial);
        reduce_squash_f<NSETS><<<256, 256, 0, stream>>>(partial, outv);
        fused_pass<2><<<pg, 1024, 0, stream>>>(xT, wq, outv, logits0, partial);
        reduce_squash_f<NSETS><<<256, 256, 0, stream>>>(partial, outp);
    } else {
        float* partial = (float*)ws;
        float* logits = (float*)(ws + (size_t)LNBLK * BATCH * NK * NO * 4);
        float* outv = (float*)(ws + (size_t)LNBLK * BATCH * NK * NO * 4 + (size_t)BATCH * NN * NK * 4);
        dim3 grid(LNBLK, BATCH / LBB);
        const int rblocks = BATCH * NK * NO / 256;
        legacy_pass<0><<<grid, LTHREADS, 0, stream>>>(xg, Wg, nullptr, logits, partial);
        legacy_reduce<<<rblocks, 256, 0, stream>>>(partial, outv);
        legacy_pass<1><<<grid, LTHREADS, 0, stream>>>(xg, Wg, outv, logits, partial);
        legacy_reduce<<<rblocks, 256, 0, stream>>>(partial, outv);
        legacy_pass<2><<<grid, LTHREADS, 0, stream>>>(xg, Wg, outv, logits, partial);
        legacy_reduce<<<rblocks, 256, 0, stream>>>(partial, outp);
    }
}

// Round 10
// 380.217 us; speedup vs baseline: 1.2508x; 1.1726x over previous
//
#include <hip/hip_runtime.h>
#include <math.h>

// CapsuleLayer routing on MI355X (gfx950). fp32 in/out.
// B=64, n=2048, k=32, in_C=16, out_C=32, 3 routing iterations.
//
// Round-10: fused passes with NO priors LDS round-trip. MFMA orientation
// A=wq (rows o), B=xT (cols b) -> D[row=o][col=b]; lane=b, regs=o, so
// delta[b][k] = sum_o prior*out is an in-register dot + shfl_xor(32).
// Only the 32x32 delta matrix goes through LDS (x33 padded, double-buffered,
// 2 barriers/node); softmax in a thread-remapped phase (k in lanes, 4-hop
// shuffle row-sum, no max-subtraction). s accumulated via coalesced
// atomicAdd into s_glob[k][o][b] (256 KB); reduce_squash is a tiny 256 KB
// kernel that also re-zeros s_glob. Round-9 disease: 1M LDS bank conflicts
// + ~50 DS ops/wave-node staging full priors tiles through LDS (112 us).

#define BATCH 64
#define NN    2048
#define NK    32
#define NI    16
#define NO    32

#define PNB   16                  // nodes per fused block
#define NSETS (NN / PNB)          // 128 node-sets

typedef __bf16 bf16x8 __attribute__((ext_vector_type(8)));
typedef float  f32x16 __attribute__((ext_vector_type(16)));

__device__ __forceinline__ unsigned short f2bf(float f) {
    unsigned int x = __float_as_uint(f);
    unsigned int lsb = (x >> 16) & 1u;
    x += 0x7fffu + lsb;                 // RNE
    return (unsigned short)(x >> 16);
}
__device__ __forceinline__ float bflo(unsigned int u) { return __uint_as_float(u << 16); }
__device__ __forceinline__ float bfhi(unsigned int u) { return __uint_as_float(u & 0xffff0000u); }

// ---------------- fast path ----------------

__global__ __launch_bounds__(1024) void zero_kernel(float* __restrict__ p) {
    p[blockIdx.x * 1024 + threadIdx.x] = 0.f;
}

// x [b][n][i] fp32 -> xT [n][b][i] bf16
__global__ __launch_bounds__(256) void xt_kernel(const float* __restrict__ xg,
                                                 unsigned short* __restrict__ xT) {
    int id = blockIdx.x * 256 + threadIdx.x;      // 524288
    int b = id >> 13;
    int rem = id & 8191;
    int n = rem >> 2;
    int i4 = rem & 3;
    float4 v = *(const float4*)(xg + ((size_t)b * NN + n) * NI + i4 * 4);
    ushort4 o;
    o.x = f2bf(v.x); o.y = f2bf(v.y); o.z = f2bf(v.z); o.w = f2bf(v.w);
    *(ushort4*)(xT + ((size_t)n * BATCH + b) * NI + i4 * 4) = o;
}

// W fp32 [n][k][i][o] -> wq bf16 [n][k][o][i] (A-fragment-ready).
__global__ __launch_bounds__(256) void wqt_kernel(const float* __restrict__ Wg,
                                                  unsigned short* __restrict__ wq) {
    const int w    = threadIdx.x >> 6;
    const int lane = threadIdx.x & 63;
    const int task = blockIdx.x * 4 + w;          // 65536 = n*32 + k
    const int o  = lane & 31;
    const int ih = lane >> 5;                     // i-half
    const float* src = Wg + (size_t)task * (NI * NO);
    unsigned short d[8];
#pragma unroll
    for (int j = 0; j < 8; ++j)
        d[j] = f2bf(src[(ih * 8 + j) * NO + o]);
    *(uint4*)(wq + (size_t)task * (NO * NI) + o * NI + ih * 8) = *(uint4*)d;
}

// Fused routing pass. Grid (128 sets, 2 b-halves), block 1024 = 16 waves.
// Wave w owns k0=2w, k1=2w+1. MFMA: A=wq[k][o][i] (rows o), B=xT[b][i]
// (cols b) -> D rows o = (r&3)+8*(r>>2)+4*h5, col b = l5 (round-5 verified).
// Per node: mfma x2 -> in-reg delta dot + shfl_xor(32) -> delta_lds (x33
// pad, double-buffered) -> barrier -> thread-phase softmax (tid=(b,k),
// 4-hop shuffle row-sum, coalesced logits I/O) -> barrier -> probs read,
// accumulate. PASS 0: no LDS/barriers at all (uniform probs).
// End: coalesced atomicAdd into s_glob[k][o][b].
template <int PASS>
__global__ __launch_bounds__(1024) void fused_pass(
    const unsigned short* __restrict__ xT,   // bf16 [n][b][i]
    const unsigned short* __restrict__ wq,   // bf16 [n][k][o][i]
    const float* __restrict__ outv,          // fp32 [k][o][b]   (PASS>=1)
    float* __restrict__ logits0,             // fp32 [n][b][k]   (PASS>=1)
    float* __restrict__ s_glob)              // fp32 [k][o][b], pre-zeroed
{
    __shared__ float delta_lds[2][32 * 33];      // 8448 B

    const int tid  = threadIdx.x;
    const int w    = tid >> 6;                   // 0..15
    const int lane = tid & 63;
    const int l5   = lane & 31;                  // b (local) for MFMA cols
    const int h5   = lane >> 5;                  // o-half
    const int set  = blockIdx.x;
    const int hb   = blockIdx.y;
    const int k0   = 2 * w, k1 = 2 * w + 1;
    const int gb5  = hb * 32 + l5;               // global b for this lane
    const int sb   = tid >> 5;                   // softmax-phase local b
    const int sk   = tid & 31;                   // softmax-phase k
    const int nbase = set * PNB;

    // out fragments, packed bf16 pairs (regs r, r+1)
    unsigned orp0[8], orp1[8];
    if constexpr (PASS >= 1) {
#pragma unroll
        for (int q = 0; q < 8; ++q) {
            const int oA = ((2*q) & 3) + 8 * ((2*q) >> 2) + 4 * h5;
            const int oB = ((2*q+1) & 3) + 8 * ((2*q+1) >> 2) + 4 * h5;
            float a0 = outv[(k0 * NO + oA) * BATCH + gb5];
            float b0 = outv[(k0 * NO + oB) * BATCH + gb5];
            float a1 = outv[(k1 * NO + oA) * BATCH + gb5];
            float b1 = outv[(k1 * NO + oB) * BATCH + gb5];
            orp0[q] = (unsigned)f2bf(a0) | ((unsigned)f2bf(b0) << 16);
            orp1[q] = (unsigned)f2bf(a1) | ((unsigned)f2bf(b1) << 16);
        }
    }

    float sa0[16], sa1[16];
#pragma unroll
    for (int r = 0; r < 16; ++r) { sa0[r] = 0.f; sa1[r] = 0.f; }

    // depth-1 prefetch
    bf16x8 aN, b0N, b1N;
    float gN = 0.f;
    {
        const int n = nbase;
        b0N = *(const bf16x8*)(wq + (size_t)n * (NK * NO * NI) + k0 * (NO * NI) + l5 * NI + h5 * 8);
        b1N = *(const bf16x8*)(wq + (size_t)n * (NK * NO * NI) + k1 * (NO * NI) + l5 * NI + h5 * 8);
        aN  = *(const bf16x8*)(xT + (size_t)n * (BATCH * NI) + gb5 * NI + h5 * 8);
        if constexpr (PASS == 2)
            gN = logits0[(size_t)n * (BATCH * NK) + hb * 1024 + tid];
    }

    int buf = 0;
    for (int j = 0; j < PNB; ++j) {
        const int n = nbase + j;
        const bf16x8 aC = aN, b0C = b0N, b1C = b1N;
        const float gC = gN;
        if (j < PNB - 1) {
            const int n2 = n + 1;
            b0N = *(const bf16x8*)(wq + (size_t)n2 * (NK * NO * NI) + k0 * (NO * NI) + l5 * NI + h5 * 8);
            b1N = *(const bf16x8*)(wq + (size_t)n2 * (NK * NO * NI) + k1 * (NO * NI) + l5 * NI + h5 * 8);
            aN  = *(const bf16x8*)(xT + (size_t)n2 * (BATCH * NI) + gb5 * NI + h5 * 8);
            if constexpr (PASS == 2)
                gN = logits0[(size_t)n2 * (BATCH * NK) + hb * 1024 + tid];
        }

        f32x16 c0, c1;
#pragma unroll
        for (int r = 0; r < 16; ++r) { c0[r] = 0.f; c1[r] = 0.f; }
        c0 = __builtin_amdgcn_mfma_f32_32x32x16_bf16(b0C, aC, c0, 0, 0, 0);  // A=wq(k0), B=x
        c1 = __builtin_amdgcn_mfma_f32_32x32x16_bf16(b1C, aC, c1, 0, 0, 0);  // A=wq(k1), B=x

        if constexpr (PASS == 0) {
#pragma unroll
            for (int r = 0; r < 16; ++r) { sa0[r] += c0[r]; sa1[r] += c1[r]; }
        } else {
            // in-register delta dot (this lane's o-half), then cross-half sum
            float d0 = 0.f, d1 = 0.f;
#pragma unroll
            for (int r = 0; r < 16; ++r) {
                const unsigned u0 = orp0[r >> 1], u1 = orp1[r >> 1];
                const float o0 = (r & 1) ? bfhi(u0) : bflo(u0);
                const float o1 = (r & 1) ? bfhi(u1) : bflo(u1);
                d0 = fmaf(c0[r], o0, d0);
                d1 = fmaf(c1[r], o1, d1);
            }
            d0 += __shfl_xor(d0, 32);
            d1 += __shfl_xor(d1, 32);

            delta_lds[buf][l5 * 33 + (h5 ? k1 : k0)] = h5 ? d1 : d0;
            __syncthreads();

            // softmax phase: tid -> (sb, sk)
            float l = delta_lds[buf][sb * 33 + sk];
            if constexpr (PASS == 1)
                logits0[(size_t)n * (BATCH * NK) + hb * 1024 + tid] = l;   // coalesced
            else
                l += gC;
            float e = __expf(l);             // no max-subtraction: |l| <= ~8
            float s = e;
#pragma unroll
            for (int mask = 1; mask < 32; mask <<= 1)
                s += __shfl_xor(s, mask);
            delta_lds[buf][sb * 33 + sk] = e / s;    // own slot: no race
            __syncthreads();

            const float p0 = delta_lds[buf][l5 * 33 + k0];
            const float p1 = delta_lds[buf][l5 * 33 + k1];
#pragma unroll
            for (int r = 0; r < 16; ++r) {
                sa0[r] = fmaf(p0, c0[r], sa0[r]);
                sa1[r] = fmaf(p1, c1[r], sa1[r]);
            }
            buf ^= 1;
        }
    }

    const float scale = (PASS == 0) ? (1.f / NK) : 1.f;
#pragma unroll
    for (int r = 0; r < 16; ++r) {
        const int o = (r & 3) + 8 * (r >> 2) + 4 * h5;
        atomicAdd(&s_glob[(k0 * NO + o) * BATCH + gb5], sa0[r] * scale);
        atomicAdd(&s_glob[(k1 * NO + o) * BATCH + gb5], sa1[r] * scale);
    }
}

// Squash s_glob[k][o][b] -> outv [k][o][b] (or final outp [b][1][k][o]);
// re-zeros s_glob for the next pass. Grid 32 (one block per k).
template <int FINAL>
__global__ __launch_bounds__(1024) void reduce_squash2(
    float* __restrict__ s_glob,
    float* __restrict__ outv,
    float* __restrict__ outp)
{
    __shared__ float red[2048];
    __shared__ float coef[64];
    const int k = blockIdx.x;
    const int t = threadIdx.x;
    const int o = t >> 6;          // 0..15
    const int b = t & 63;
    float* base = s_glob + k * 2048;
    float va = base[o * 64 + b];
    float vb = base[(o + 16) * 64 + b];
    base[o * 64 + b] = 0.f;
    base[(o + 16) * 64 + b] = 0.f;
    red[o * 64 + b] = va * va;
    red[(o + 16) * 64 + b] = vb * vb;
    __syncthreads();
    if (t < 64) {
        float sq = 0.f;
#pragma unroll
        for (int oo = 0; oo < 32; ++oo) sq += red[oo * 64 + t];
        coef[t] = sq / ((1.f + sq) * sqrtf(sq));
    }
    __syncthreads();
    const float cf = coef[b];
    if (FINAL) {
        outp[b * 1024 + k * 32 + o]      = va * cf;
        outp[b * 1024 + k * 32 + o + 16] = vb * cf;
    } else {
        outv[k * 2048 + o * 64 + b]        = va * cf;
        outv[k * 2048 + (o + 16) * 64 + b] = vb * cf;
    }
}

// ---------------- legacy fallback (round-2 code, known-good 582 us) ----------------

#define LBB 32
#define LNCHUNK 8
#define LNBLK (NN / LNCHUNK)
#define LTHREADS 512
#define WK_STRIDE 516

template <int PASS>
__global__ __launch_bounds__(LTHREADS, 1) void legacy_pass(
    const float* __restrict__ xg, const float* __restrict__ Wg,
    const float* __restrict__ outvL, float* __restrict__ logits,
    float* __restrict__ partial)
{
    __shared__ float w_lds[NK * WK_STRIDE];
    __shared__ float x_lds[LBB][NI + 1];
    __shared__ float delta_lds[LBB][NK + 1];
    const int t = threadIdx.x, nb = blockIdx.x, bg = blockIdx.y;
    const int b0 = bg * LBB;
    const int k = t >> 4, bq = t & 15, bl0 = bq * 2, bl1 = bq * 2 + 1;
    float acc0[NO], acc1[NO];
#pragma unroll
    for (int o = 0; o < NO; ++o) { acc0[o] = 0.f; acc1[o] = 0.f; }
    float outr0[NO], outr1[NO];
    if constexpr (PASS >= 1) {
        const float4* o0 = (const float4*)&outvL[((b0 + bl0) * NK + k) * NO];
        const float4* o1 = (const float4*)&outvL[((b0 + bl1) * NK + k) * NO];
#pragma unroll
        for (int q = 0; q < NO / 4; ++q) {
            float4 a = o0[q]; float4 b = o1[q];
            outr0[4*q+0]=a.x; outr0[4*q+1]=a.y; outr0[4*q+2]=a.z; outr0[4*q+3]=a.w;
            outr1[4*q+0]=b.x; outr1[4*q+1]=b.y; outr1[4*q+2]=b.z; outr1[4*q+3]=b.w;
        }
    }
    for (int j = 0; j < LNCHUNK; ++j) {
        const int n = nb * LNCHUNK + j;
        __syncthreads();
        {
            const float4* src = (const float4*)(Wg + (size_t)n * (NK * NI * NO));
#pragma unroll
            for (int r = 0; r < (NK * NI * NO / 4) / LTHREADS; ++r) {
                int idx4 = t + r * LTHREADS;
                float4 v = src[idx4];
                int e = idx4 * 4, kk = e >> 9, rem = e & 511;
                *(float4*)&w_lds[kk * WK_STRIDE + rem] = v;
            }
        }
        { int bl = t >> 4, i = t & 15;
          x_lds[bl][i] = xg[((size_t)(b0 + bl) * NN + n) * NI + i]; }
        __syncthreads();
        if constexpr (PASS == 0) {
#pragma unroll
            for (int i = 0; i < NI; ++i) {
                float xa = x_lds[bl0][i], xb = x_lds[bl1][i];
                const float* wrow = &w_lds[k * WK_STRIDE + i * NO];
#pragma unroll
                for (int o = 0; o < NO; ++o) {
                    float w = wrow[o];
                    acc0[o] = fmaf(xa, w, acc0[o]);
                    acc1[o] = fmaf(xb, w, acc1[o]);
                }
            }
        } else {
            float pr0[NO], pr1[NO];
#pragma unroll
            for (int o = 0; o < NO; ++o) { pr0[o] = 0.f; pr1[o] = 0.f; }
#pragma unroll
            for (int i = 0; i < NI; ++i) {
                float xa = x_lds[bl0][i], xb = x_lds[bl1][i];
                const float* wrow = &w_lds[k * WK_STRIDE + i * NO];
#pragma unroll
                for (int o = 0; o < NO; ++o) {
                    float w = wrow[o];
                    pr0[o] = fmaf(xa, w, pr0[o]);
                    pr1[o] = fmaf(xb, w, pr1[o]);
                }
            }
            float d0 = 0.f, d1 = 0.f;
#pragma unroll
            for (int o = 0; o < NO; ++o) {
                d0 = fmaf(pr0[o], outr0[o], d0);
                d1 = fmaf(pr1[o], outr1[o], d1);
            }
            float l0 = d0, l1 = d1;
            const size_t li0 = ((size_t)(b0 + bl0) * NN + n) * NK + k;
            const size_t li1 = ((size_t)(b0 + bl1) * NN + n) * NK + k;
            if constexpr (PASS == 2) { l0 += logits[li0]; l1 += logits[li1]; }
            else { logits[li0] = d0; logits[li1] = d1; }
            delta_lds[bl0][k] = l0; delta_lds[bl1][k] = l1;
            __syncthreads();
            float m0 = -1e30f, m1 = -1e30f;
#pragma unroll
            for (int kk = 0; kk < NK; ++kk) {
                m0 = fmaxf(m0, delta_lds[bl0][kk]);
                m1 = fmaxf(m1, delta_lds[bl1][kk]);
            }
            float s0 = 0.f, s1 = 0.f;
#pragma unroll
            for (int kk = 0; kk < NK; ++kk) {
                s0 += __expf(delta_lds[bl0][kk] - m0);
                s1 += __expf(delta_lds[bl1][kk] - m1);
            }
            float p0 = __expf(l0 - m0) / s0;
            float p1 = __expf(l1 - m1) / s1;
#pragma unroll
            for (int o = 0; o < NO; ++o) {
                acc0[o] = fmaf(p0, pr0[o], acc0[o]);
                acc1[o] = fmaf(p1, pr1[o], acc1[o]);
            }
        }
    }
    const float scale = (PASS == 0) ? (1.f / NK) : 1.f;
    float4* p0 = (float4*)&partial[(((size_t)nb * BATCH + (b0 + bl0)) * NK + k) * NO];
    float4* p1 = (float4*)&partial[(((size_t)nb * BATCH + (b0 + bl1)) * NK + k) * NO];
#pragma unroll
    for (int q = 0; q < NO / 4; ++q) {
        float4 v0, v1;
        v0.x = acc0[4*q+0]*scale; v0.y = acc0[4*q+1]*scale;
        v0.z = acc0[4*q+2]*scale; v0.w = acc0[4*q+3]*scale;
        v1.x = acc1[4*q+0]*scale; v1.y = acc1[4*q+1]*scale;
        v1.z = acc1[4*q+2]*scale; v1.w = acc1[4*q+3]*scale;
        p0[q] = v0; p1[q] = v1;
    }
}

__global__ __launch_bounds__(256) void legacy_reduce(
    const float* __restrict__ partial, float* __restrict__ outf)
{
    const int tid = blockIdx.x * 256 + threadIdx.x;
    float v = 0.f;
    for (int nb = 0; nb < LNBLK; ++nb)
        v += partial[(size_t)nb * (BATCH * NK * NO) + tid];
    float sq = v * v;
#pragma unroll
    for (int off = 1; off < 32; off <<= 1) sq += __shfl_xor(sq, off);
    float coef = sq / ((1.f + sq) * sqrtf(sq));
    outf[tid] = v * coef;
}

// ---------------- launch ----------------

extern "C" void kernel_launch(void* const* d_in, const int* in_sizes, int n_in,
                              void* d_out, int out_size, void* d_ws, size_t ws_size,
                              hipStream_t stream)
{
    const float* xg = (const float*)d_in[0];
    const float* Wg = (const float*)d_in[1];
    float* outp = (float*)d_out;
    char* ws = (char*)d_ws;

    const size_t SZ_WQ     = (size_t)NN * NK * NO * NI * 2;          //  64 MiB
    const size_t SZ_XT     = (size_t)NN * BATCH * NI * 2;            //   4 MiB
    const size_t SZ_LOGITS = (size_t)NN * BATCH * NK * 4;            //  16 MiB
    const size_t SZ_SG     = (size_t)NK * NO * BATCH * 4;            // 256 KiB
    const size_t SZ_OUTV   = (size_t)NK * NO * BATCH * 4;            // 256 KiB
    const size_t NEED = SZ_WQ + SZ_XT + SZ_LOGITS + SZ_SG + SZ_OUTV;

    if (ws_size >= NEED) {
        unsigned short* wq = (unsigned short*)ws;
        unsigned short* xT = (unsigned short*)(ws + SZ_WQ);
        float* logits0 = (float*)(ws + SZ_WQ + SZ_XT);
        float* s_glob  = (float*)(ws + SZ_WQ + SZ_XT + SZ_LOGITS);
        float* outv    = (float*)(ws + SZ_WQ + SZ_XT + SZ_LOGITS + SZ_SG);

        zero_kernel<<<64, 1024, 0, stream>>>(s_glob);
        xt_kernel<<<2048, 256, 0, stream>>>(xg, xT);
        wqt_kernel<<<16384, 256, 0, stream>>>(Wg, wq);

        dim3 pg(NSETS, 2);
        fused_pass<0><<<pg, 1024, 0, stream>>>(xT, wq, nullptr, nullptr, s_glob);
        reduce_squash2<0><<<32, 1024, 0, stream>>>(s_glob, outv, nullptr);
        fused_pass<1><<<pg, 1024, 0, stream>>>(xT, wq, outv, logits0, s_glob);
        reduce_squash2<0><<<32, 1024, 0, stream>>>(s_glob, outv, nullptr);
        fused_pass<2><<<pg, 1024, 0, stream>>>(xT, wq, outv, logits0, s_glob);
        reduce_squash2<1><<<32, 1024, 0, stream>>>(s_glob, nullptr, outp);
    } else {
        float* partial = (float*)ws;
        float* logits = (float*)(ws + (size_t)LNBLK * BATCH * NK * NO * 4);
        float* outvL = (float*)(ws + (size_t)LNBLK * BATCH * NK * NO * 4 + (size_t)BATCH * NN * NK * 4);
        dim3 grid(LNBLK, BATCH / LBB);
        const int rblocks = BATCH * NK * NO / 256;
        legacy_pass<0><<<grid, LTHREADS, 0, stream>>>(xg, Wg, nullptr, logits, partial);
        legacy_reduce<<<rblocks, 256, 0, stream>>>(partial, outvL);
        legacy_pass<1><<<grid, LTHREADS, 0, stream>>>(xg, Wg, outvL, logits, partial);
        legacy_reduce<<<rblocks, 256, 0, stream>>>(partial, outvL);
        legacy_pass<2><<<grid, LTHREADS, 0, stream>>>(xg, Wg, outvL, logits, partial);
        legacy_reduce<<<rblocks, 256, 0, stream>>>(partial, outp);
    }
}